// Round 4
// baseline (2243.646 us; speedup 1.0000x reference)
//
#include <hip/hip_runtime.h>
#include <cstddef>

typedef unsigned short u16;
typedef unsigned int u32;

#define N 384
#define NELEM (N*N)        // 147456
#define NCH 128
#define NMAT 256
#define EPS 1e-5f

// Muon quintic coefficients
#define QA 3.4445f
#define QB (-4.7750f)
#define QC 2.0315f

typedef __attribute__((ext_vector_type(8))) short bf16x8;   // 8 bf16 = 4 VGPRs
typedef __attribute__((ext_vector_type(4))) float f32x4;

__device__ __forceinline__ float bf2f(u16 h){ union{u32 u; float f;} v; v.u=((u32)h)<<16; return v.f; }
__device__ __forceinline__ u16 f2bf(float x){
  union{float f;u32 u;} v; v.f=x;
  u32 r=(v.u + 0x7FFFu + ((v.u>>16)&1u))>>16;   // RNE
  return (u16)r;
}

__device__ __forceinline__ float wave_sum(float v){
#pragma unroll
  for(int o=32;o>0;o>>=1) v += __shfl_down(v,o,64);
  return v;
}

__device__ __forceinline__ const float* mat_src(const float* ir, const float* vi, int m){
  return (m < NCH) ? (ir + (size_t)m*NELEM) : (vi + (size_t)(m-NCH)*NELEM);
}

__global__ void k_zero(float* __restrict__ x, int n){
  int i = blockIdx.x*256 + threadIdx.x;
  if(i < n) x[i] = 0.f;
}

// partial Frobenius^2 of (M+eps): grid (CH, 16), atomicAdd into f[mloc]
__global__ __launch_bounds__(256)
void k_frob_part(const float* __restrict__ ir, const float* __restrict__ vi,
                 float* __restrict__ f, int m0){
  int mloc = blockIdx.x;
  const float4* s4 = (const float4*)mat_src(ir, vi, m0+mloc) + blockIdx.y*(NELEM/4/16);
  float s = 0.f;
  for(int i=threadIdx.x; i<NELEM/4/16; i+=256){
    float4 v = s4[i];
    float a=v.x+EPS, b=v.y+EPS, c=v.z+EPS, d=v.w+EPS;
    s += a*a + b*b + c*c + d*d;
  }
  __shared__ float sm[4];
  int lane=threadIdx.x&63, w=threadIdx.x>>6;
  s = wave_sum(s);
  if(lane==0) sm[w]=s;
  __syncthreads();
  if(threadIdx.x==0) atomicAdd(&f[mloc], sm[0]+sm[1]+sm[2]+sm[3]);
}

// Fused: X = bf16((M+eps)*rsqrt(f)) AND Y = X^T, one pass. grid (6,6,CH).
__global__ __launch_bounds__(256)
void k_init_t(const float* __restrict__ ir, const float* __restrict__ vi,
              const float* __restrict__ f, u16* __restrict__ Xg,
              u16* __restrict__ Yg, int m0){
  __shared__ u16 t[64][68];
  int mloc = blockIdx.z;
  const float* Ms = mat_src(ir, vi, m0+mloc);
  float inv = rsqrtf(f[mloc]);
  size_t mat = (size_t)mloc*NELEM;
  u16* X = Xg + mat; u16* Y = Yg + mat;
  int bx = blockIdx.x*64, by = blockIdx.y*64;
  int c = (threadIdx.x&15)*4, r0 = threadIdx.x>>4;
#pragma unroll
  for(int s=0;s<4;s++){
    int r = r0 + s*16;
    float4 v = *(const float4*)&Ms[(size_t)(by+r)*N + bx + c];
    ushort4 o;
    o.x=f2bf((v.x+EPS)*inv); o.y=f2bf((v.y+EPS)*inv);
    o.z=f2bf((v.z+EPS)*inv); o.w=f2bf((v.w+EPS)*inv);
    *(ushort4*)&X[(size_t)(by+r)*N + bx + c] = o;
    t[r][c]=o.x; t[r][c+1]=o.y; t[r][c+2]=o.z; t[r][c+3]=o.w;
  }
  __syncthreads();
#pragma unroll
  for(int s=0;s<4;s++){
    int r = r0 + s*16;
    ushort4 v;
    v.x=t[c+0][r]; v.y=t[c+1][r]; v.z=t[c+2][r]; v.w=t[c+3][r];
    *(ushort4*)&Y[(size_t)(bx+r)*N + by + c] = v;
  }
}

__device__ __forceinline__ void stage4(const u16* pa0, const u16* pa1,
                                       const u16* pb0, const u16* pb1,
                                       u16* la0, u16* la1, u16* lb0, u16* lb1){
  __builtin_amdgcn_global_load_lds((const __attribute__((address_space(1))) void*)pa0,
                                   (__attribute__((address_space(3))) void*)la0, 16, 0, 0);
  __builtin_amdgcn_global_load_lds((const __attribute__((address_space(1))) void*)pa1,
                                   (__attribute__((address_space(3))) void*)la1, 16, 0, 0);
  __builtin_amdgcn_global_load_lds((const __attribute__((address_space(1))) void*)pb0,
                                   (__attribute__((address_space(3))) void*)lb0, 16, 0, 0);
  __builtin_amdgcn_global_load_lds((const __attribute__((address_space(1))) void*)pb1,
                                   (__attribute__((address_space(3))) void*)lb1, 16, 0, 0);
}

// NT GEMM: C = alpha*(P*Q^T) + beta*D, optional transposed store to Tg.
// sym=1: 6 upper-tri tiles/matrix, mirror into Tg(=Cg), skip mirror on diag.
// XCD-pinned 1D grid. XOR-swizzled LDS (swizzle source column; readers invert).
// Double-buffered K-loop: prefetch slab k+1 after the barrier, before consuming
// slab k -> loads have the whole compute phase in flight.
// do_trace: skip all stores; instead atomicAdd sum(C .* (Msrc+EPS)) into pvec.
__global__ __launch_bounds__(256)
void k_gemm(const u16* __restrict__ Pg, const u16* __restrict__ Qg,
            u16* __restrict__ Cg, u16* __restrict__ Tg,
            const u16* __restrict__ Dg, float alpha, float beta, int sym,
            const float* __restrict__ irv, const float* __restrict__ viv,
            float* __restrict__ pvec, int m0, int do_trace){
  __shared__ __align__(16) u16 As[2*128*32];
  __shared__ __align__(16) u16 Bs[2*128*32];
  int tid = threadIdx.x, lane = tid&63, w = tid>>6;

  int T = sym ? 6 : 9;
  int CH = gridDim.x / T;
  int m, t;
  if((CH & 7) == 0){
    int xcd = blockIdx.x & 7;
    int b2  = blockIdx.x >> 3;
    t = b2 % T;
    m = xcd + 8*(b2 / T);
  } else {
    m = blockIdx.x / T;
    t = blockIdx.x - m*T;
  }
  int i0, j0;
  if(sym){
    const int it[6]={0,0,0,1,1,2};
    const int jt[6]={0,1,2,1,2,2};
    i0=it[t]; j0=jt[t];
  } else {
    i0 = t/3; j0 = t - 3*i0;
  }
  size_t mat = (size_t)m*NELEM;
  const u16* P = Pg + mat + (size_t)(i0*128)*N;
  const u16* Q = Qg + mat + (size_t)(j0*128)*N;

  // staging: per wave 2 A + 2 B instrs; instr s covers rows (w*2+s)*16..+15.
  // source column swizzled: chunk = q0 ^ ((srow>>1)&3)
  int srow = lane>>2;                       // 0..15
  int q0   = lane&3;
  int scol = (q0 ^ ((srow>>1)&3)) * 8;      // u16 offset in 32-wide k slice
  const u16* pa0 = P + (size_t)((w*2+0)*16 + srow)*N + scol;
  const u16* pa1 = P + (size_t)((w*2+1)*16 + srow)*N + scol;
  const u16* pb0 = Q + (size_t)((w*2+0)*16 + srow)*N + scol;
  const u16* pb1 = Q + (size_t)((w*2+1)*16 + srow)*N + scol;
  int lo0 = (w*2+0)*512 + lane*8;
  int lo1 = (w*2+1)*512 + lane*8;

  f32x4 acc[4][4];
#pragma unroll
  for(int r=0;r<4;r++)
#pragma unroll
    for(int c=0;c<4;c++) acc[r][c] = (f32x4)0.f;

  int wm = (w&1)*64, wn = (w>>1)*64;
  int quad = lane>>4, ln = lane&15;
  int swz = (quad ^ ((ln>>1)&3)) * 8;       // inverse swizzle for fragment reads

  // prefetch slab 0 into buffer 0
  stage4(pa0, pa1, pb0, pb1, &As[lo0], &As[lo1], &Bs[lo0], &Bs[lo1]);

  for(int kk=0;kk<12;kk++){
    int cur = kk&1, nxt = cur^1;
    __syncthreads();                        // waits slab kk's loads; frees buf nxt
    if(kk<11){
      int k0 = (kk+1)*32;
      stage4(pa0+k0, pa1+k0, pb0+k0, pb1+k0,
             &As[nxt*4096+lo0], &As[nxt*4096+lo1],
             &Bs[nxt*4096+lo0], &Bs[nxt*4096+lo1]);
    }
    const u16* Ab = &As[cur*4096];
    const u16* Bb = &Bs[cur*4096];
    bf16x8 af[4], bv[4];
#pragma unroll
    for(int r=0;r<4;r++) af[r] = *(const bf16x8*)&Ab[(wm + r*16 + ln)*32 + swz];
#pragma unroll
    for(int c=0;c<4;c++) bv[c] = *(const bf16x8*)&Bb[(wn + c*16 + ln)*32 + swz];
#pragma unroll
    for(int r=0;r<4;r++)
#pragma unroll
      for(int c=0;c<4;c++)
        acc[r][c] = __builtin_amdgcn_mfma_f32_16x16x32_bf16(af[r], bv[c], acc[r][c], 0, 0, 0);
  }

  // epilogue
  const u16* D = Dg ? Dg + mat : nullptr;
  int rowb = i0*128 + wm, colb = j0*128 + wn;

  if(do_trace){
    const float* Ms = mat_src(irv, viv, m0 + m);
    float s = 0.f;
#pragma unroll
    for(int r=0;r<4;r++){
#pragma unroll
      for(int c=0;c<4;c++){
        int row0 = rowb + r*16 + quad*4;
        int col  = colb + c*16 + ln;
        float v0 = alpha*acc[r][c].x;
        float v1 = alpha*acc[r][c].y;
        float v2 = alpha*acc[r][c].z;
        float v3 = alpha*acc[r][c].w;
        if(D){
          v0 += beta*bf2f(D[(size_t)(row0+0)*N + col]);
          v1 += beta*bf2f(D[(size_t)(row0+1)*N + col]);
          v2 += beta*bf2f(D[(size_t)(row0+2)*N + col]);
          v3 += beta*bf2f(D[(size_t)(row0+3)*N + col]);
        }
        s += v0*(Ms[(size_t)(row0+0)*N + col]+EPS)
           + v1*(Ms[(size_t)(row0+1)*N + col]+EPS)
           + v2*(Ms[(size_t)(row0+2)*N + col]+EPS)
           + v3*(Ms[(size_t)(row0+3)*N + col]+EPS);
      }
    }
    s = wave_sum(s);
    float* smf = (float*)As;               // reuse LDS
    if(lane==0) smf[w]=s;
    __syncthreads();
    if(tid==0) atomicAdd(&pvec[m0+m], smf[0]+smf[1]+smf[2]+smf[3]);
    return;
  }

  u16* C = Cg + mat;
  bool do_t = (Tg != nullptr) && !(sym && (i0==j0));
  u16* Tm = Tg ? Tg + mat : nullptr;
#pragma unroll
  for(int r=0;r<4;r++){
#pragma unroll
    for(int c=0;c<4;c++){
      int row0 = rowb + r*16 + quad*4;
      int col  = colb + c*16 + ln;
      float v0 = alpha*acc[r][c].x;
      float v1 = alpha*acc[r][c].y;
      float v2 = alpha*acc[r][c].z;
      float v3 = alpha*acc[r][c].w;
      if(D){
        v0 += beta*bf2f(D[(size_t)(row0+0)*N + col]);
        v1 += beta*bf2f(D[(size_t)(row0+1)*N + col]);
        v2 += beta*bf2f(D[(size_t)(row0+2)*N + col]);
        v3 += beta*bf2f(D[(size_t)(row0+3)*N + col]);
      }
      u16 h0=f2bf(v0), h1=f2bf(v1), h2=f2bf(v2), h3=f2bf(v3);
      C[(size_t)(row0+0)*N + col] = h0;
      C[(size_t)(row0+1)*N + col] = h1;
      C[(size_t)(row0+2)*N + col] = h2;
      C[(size_t)(row0+3)*N + col] = h3;
      if(do_t){
        ushort4 pk; pk.x=h0; pk.y=h1; pk.z=h2; pk.w=h3;
        *(ushort4*)&Tm[(size_t)col*N + row0] = pk;   // T[col][row0..row0+3]
      }
    }
  }
}

__global__ void k_weights(const float* __restrict__ p, float* __restrict__ w1, float* __restrict__ w2){
  int c = threadIdx.x;
  if(c < NCH){
    float a = p[c], b = p[c+NCH];
    float den = a + b + EPS;
    w1[c] = a/den;
    w2[c] = b/den;
  }
}

__global__ __launch_bounds__(256)
void k_combine(const float* __restrict__ ir, const float* __restrict__ vi,
               const float* __restrict__ w1, const float* __restrict__ w2,
               float* __restrict__ out){
  int i = blockIdx.x*256 + threadIdx.x;
  int c = i / (NELEM/4);
  float4 a = ((const float4*)ir)[i];
  float4 b = ((const float4*)vi)[i];
  float x1 = w1[c], x2 = w2[c];
  float4 o;
  o.x = x1*a.x + x2*b.x; o.y = x1*a.y + x2*b.y;
  o.z = x1*a.z + x2*b.z; o.w = x1*a.w + x2*b.w;
  ((float4*)out)[i] = o;
}

extern "C" void kernel_launch(void* const* d_in, const int* in_sizes, int n_in,
                              void* d_out, int out_size, void* d_ws, size_t ws_size,
                              hipStream_t stream){
  const float* ir = (const float*)d_in[0];
  const float* vi = (const float*)d_in[1];
  float* out = (float*)d_out;

  // 4 bf16 buffers of CH matrices + small fp32 tail
  int CH = NMAT;
  while(CH > 1 && (size_t)4*CH*NELEM*2 + 4096 > ws_size) CH >>= 1;

  u16* b[4];
  for(int i=0;i<4;i++) b[i] = (u16*)d_ws + (size_t)i*CH*NELEM;
  float* tail = (float*)((u16*)d_ws + (size_t)4*CH*NELEM);
  float* p  = tail;          // NMAT
  float* w1 = p + NMAT;      // NCH
  float* w2 = w1 + NCH;      // NCH
  float* f  = w2 + NCH;      // CH

  k_zero<<<1,256,0,stream>>>(p, NMAT);
  for(int m0=0; m0<NMAT; m0+=CH){
    k_zero<<<1,256,0,stream>>>(f, CH);
    k_frob_part<<<dim3(CH,16),256,0,stream>>>(ir, vi, f, m0);
    k_init_t<<<dim3(6,6,CH),256,0,stream>>>(ir, vi, f, b[0], b[1], m0);

    int X=0, Y=1, f1=2, f2=3;
    dim3 gs(6*CH), gf(9*CH);
    // 5 quintic iterations: G=X^T X (via NT(Y,Y)); E=QB*G+QC*G^2; X'=QA*X+X*E; Y'=X'^T
    for(int q=0;q<5;q++){
      k_gemm<<<gs,256,0,stream>>>(b[Y],  b[Y],  b[f1], b[f1], nullptr, 1.f, 0.f, 1,
                                  nullptr, nullptr, nullptr, 0, 0);
      k_gemm<<<gs,256,0,stream>>>(b[f1], b[f1], b[f2], b[f2], b[f1],   QC,  QB,  1,
                                  nullptr, nullptr, nullptr, 0, 0);
      k_gemm<<<gf,256,0,stream>>>(b[X],  b[f2], b[f1], b[Y],  b[X],    1.f, QA,  0,
                                  nullptr, nullptr, nullptr, 0, 0);
      int tt=X; X=f1; f1=tt;
    }
    // 3 cubic polish: X' = 1.5X - 0.5*X*G ; last one fuses the trace, no stores
    for(int q=0;q<3;q++){
      k_gemm<<<gs,256,0,stream>>>(b[Y], b[Y],  b[f1], b[f1], nullptr, 1.f, 0.f, 1,
                                  nullptr, nullptr, nullptr, 0, 0);
      int last = (q==2);
      k_gemm<<<gf,256,0,stream>>>(b[X], b[f1], b[f2], last?nullptr:b[Y], b[X], -0.5f, 1.5f, 0,
                                  ir, vi, p, m0, last);
      int tt=X; X=f2; f2=tt;
    }
  }
  k_weights<<<1,128,0,stream>>>(p, w1, w2);
  k_combine<<<(NCH*(NELEM/4))/256,256,0,stream>>>(ir, vi, w1, w2, out);
}